// Round 10
// baseline (215.327 us; speedup 1.0000x reference)
//
#include <hip/hip_runtime.h>
#include <math.h>

#define B 128
#define T 1024
#define H 256
#define L 16
#define INV_TEMP (1.0f/0.07f)
#define NEG_INF -1e30f

// ws layout:
//   ws_proto : float[B][L][H]   FINAL prototypes (divided)   2 MB
//   ws_cnt   : int[B][L]        final label counts           8 KB

// ---------------------------------------------------------------------------
// Kernel 1 (v9, unchanged — proven): finalizing gather. Block = (b, 64-float
// H-chunk); counting-sorts ALL len tokens into ushort idx lists (32 KB), then
// thread (l, cs) gathers cnt[l] member rows and writes the FINAL divided
// prototype. grid = B*4 = 512 blocks, 256 thr.
__global__ __launch_bounds__(256) void proto_kernel(
    const float* __restrict__ feat, const int* __restrict__ dlen,
    const int* __restrict__ labels, float* __restrict__ ws_proto,
    int* __restrict__ ws_cnt, float* __restrict__ out) {
  __shared__ unsigned short idx[L][T];   // 32 KB token lists per label
  __shared__ int cnt[L];

  const int bx = blockIdx.x;
  if (bx == 0 && threadIdx.x == 0) out[0] = 0.f;   // replaces memset dispatch

  const int b = bx >> 2;
  const int ch = bx & 3;          // 64-float chunk of H
  const int tid = threadIdx.x;
  const int len = dlen[b];        // >= 1 always

  if (tid < L) cnt[tid] = 0;
  __syncthreads();
  for (int t = tid; t < len; t += 256) {
    const int l = labels[(size_t)b * T + t];
    const int p = atomicAdd(&cnt[l], 1);   // <=1024 int atomics: cheap
    idx[l][p] = (unsigned short)t;
  }
  __syncthreads();

  const int l = tid >> 4;         // owned label
  const int cs = tid & 15;        // owned float4 within the 64-float chunk
  const float4* fb4 = (const float4*)feat +
      (size_t)b * T * (H / 4) + ch * 16 + cs;

  const int c = cnt[l];
  float4 a = make_float4(0.f, 0.f, 0.f, 0.f);
  int i = 0;
  for (; i + 8 <= c; i += 8) {    // 8 independent loads in flight
    int t8[8];
#pragma unroll
    for (int u = 0; u < 8; ++u) t8[u] = idx[l][i + u];
    float4 f8[8];
#pragma unroll
    for (int u = 0; u < 8; ++u) f8[u] = fb4[(size_t)t8[u] * (H / 4)];
#pragma unroll
    for (int u = 0; u < 8; ++u) {
      a.x += f8[u].x; a.y += f8[u].y; a.z += f8[u].z; a.w += f8[u].w;
    }
  }
  for (; i < c; ++i) {
    const float4 f = fb4[(size_t)idx[l][i] * (H / 4)];
    a.x += f.x; a.y += f.y; a.z += f.z; a.w += f.w;
  }

  const float inv = (c > 0) ? 1.f / (float)c : 0.f;
  a.x *= inv; a.y *= inv; a.z *= inv; a.w *= inv;
  *(float4*)(ws_proto + ((size_t)b * L + l) * H + ch * 64 + cs * 4) = a;
  if (ch == 0 && tid < L) ws_cnt[b * L + tid] = cnt[tid];
}

// ---------------------------------------------------------------------------
// Kernel 2 (v10): fused dots+loss, v9 hot loop VERBATIM (K=2 token sharing,
// compiler-scheduled `unroll 2` — ~84 VGPR, spill-free), but at finer
// granularity: grid = B*8 eighths of 128 tokens, 128 thr (ts in [0,64),
// hh = wave = H-half). LDS 25 KB -> 4 blocks/CU (vs v9's 2): same wave count,
// 2x independent load streams + finer length balance. Epilogue reduction is
// a wave-0 shuffle (removes red[] + 8 barriers; proven safe in R7).
// NO early prefetch, NO manual ping-pong (R8's spill causes).
__global__ __launch_bounds__(128) void dotsloss_kernel(
    const float* __restrict__ feat, const int* __restrict__ dlen,
    const int* __restrict__ labels, const float* __restrict__ ws_proto,
    const int* __restrict__ ws_cnt, float* __restrict__ out) {
  __shared__ float pr[L * H];          // 16 KB prototypes, full H
  __shared__ float part[128][L + 1];   // 8.7 KB padded cross-half partials
  __shared__ int cnts[L];

  const int b = blockIdx.x >> 3;
  const int e = blockIdx.x & 7;        // 128-token eighth
  const int tid = threadIdx.x;

  const int len = dlen[b];
  if (e * 128 >= len) return;          // uniform exit

  if (tid < L) cnts[tid] = ws_cnt[b * L + tid];
  __syncthreads();

  // stage prototypes: pure copy, 8 iters of float4
  const float4* gp4 = (const float4*)(ws_proto + (size_t)b * L * H);
  for (int i = tid; i < L * H / 4; i += 128) ((float4*)pr)[i] = gp4[i];
  __syncthreads();

  const int ts = tid & 63;
  const int hh = tid >> 6;             // H-half; constant within each wave
  const int t0 = e * 128 + ts;
  const int t1 = t0 + 64;              // always < T: loads safe, value masked

  const float4* fA = (const float4*)feat + ((size_t)b * T + t0) * (H / 4) + hh * 32;
  const float4* fB = (const float4*)feat + ((size_t)b * T + t1) * (H / 4) + hh * 32;

  float dot0[L], dot1[L];
#pragma unroll
  for (int l = 0; l < L; ++l) { dot0[l] = 0.f; dot1[l] = 0.f; }

#pragma unroll 2
  for (int cb = 0; cb < 8; ++cb) {   // 16-float chunks of this 128-float half
    float4 fa[4], fb_[4];
#pragma unroll
    for (int q4 = 0; q4 < 4; ++q4) {
      fa[q4] = fA[cb * 4 + q4];
      fb_[q4] = fB[cb * 4 + q4];
    }
#pragma unroll
    for (int q4 = 0; q4 < 4; ++q4) {
#pragma unroll
      for (int l = 0; l < L; ++l) {
        const float4 p = *(const float4*)&pr[l * H + hh * 128 + cb * 16 + q4 * 4];
        dot0[l] += fa[q4].x * p.x + fa[q4].y * p.y +
                   fa[q4].z * p.z + fa[q4].w * p.w;
        dot1[l] += fb_[q4].x * p.x + fb_[q4].y * p.y +
                   fb_[q4].z * p.z + fb_[q4].w * p.w;
      }
    }
  }

  // cross-half combine: hh=1 publishes, hh=0 finishes
  if (hh == 1) {
#pragma unroll
    for (int l = 0; l < L; ++l) {
      part[ts][l] = dot0[l];
      part[ts + 64][l] = dot1[l];
    }
  }
  __syncthreads();

  if (hh == 0) {
    float tok = 0.f;
#pragma unroll
    for (int k = 0; k < 2; ++k) {
      const int t = t0 + k * 64;
      if (t < len) {
        float lg[L];
#pragma unroll
        for (int l = 0; l < L; ++l) {
          const float d = (k == 0 ? dot0[l] : dot1[l]) + part[ts + k * 64][l];
          lg[l] = (cnts[l] > 0) ? d * INV_TEMP : NEG_INF;
        }
        float m = lg[0];
#pragma unroll
        for (int l = 1; l < L; ++l) m = fmaxf(m, lg[l]);
        float se = 0.f;
#pragma unroll
        for (int l = 0; l < L; ++l) se += expf(lg[l] - m);
        const float lsp = m + logf(se);

        const int lab = labels[(size_t)b * T + t];
        float pos = 0.f;
#pragma unroll
        for (int l = 0; l < L; ++l) pos += (l == lab) ? lg[l] : 0.f;

        tok += lsp - pos;
      }
    }
    // wave-0 shuffle reduction; single atomic per block
#pragma unroll
    for (int off = 32; off > 0; off >>= 1) tok += __shfl_down(tok, off, 64);
    if (ts == 0) atomicAdd(out, tok / ((float)len * (float)B));
  }
}

extern "C" void kernel_launch(void* const* d_in, const int* in_sizes, int n_in,
                              void* d_out, int out_size, void* d_ws, size_t ws_size,
                              hipStream_t stream) {
  const float* feat = (const float*)d_in[0];
  const int* dlen = (const int*)d_in[1];
  const int* labels = (const int*)d_in[2];
  float* out = (float*)d_out;

  float* ws_proto = (float*)d_ws;                          // B*L*H floats
  int* ws_cnt = (int*)(ws_proto + (size_t)B * L * H);      // B*L ints

  proto_kernel<<<B * 4, 256, 0, stream>>>(feat, dlen, labels, ws_proto,
                                          ws_cnt, out);
  dotsloss_kernel<<<B * 8, 128, 0, stream>>>(feat, dlen, labels, ws_proto,
                                             ws_cnt, out);
}